// Round 2
// baseline (1241.019 us; speedup 1.0000x reference)
//
#include <hip/hip_runtime.h>

#define T_TOK 65536
#define HDIM  1024
#define NSEG  64

typedef _Float16 half8  __attribute__((ext_vector_type(8)));
typedef float    f32x2  __attribute__((ext_vector_type(2)));
typedef float    f32x4  __attribute__((ext_vector_type(4)));
typedef float    f32x16 __attribute__((ext_vector_type(16)));

// ---- workspace layout (bytes) ----
#define WP_OFF   0ull                    // _Float16[1024*1024]: W packed fragment-major
#define U0_OFF   2097152ull              // float[1024]: gamma*Wout[:,0]
#define U1_OFF   (U0_OFF + 4096ull)     // float[1024]: gamma*Wout[:,1]
#define CON_OFF  (U1_OFF + 4096ull)     // float[4]: G0,G1,Bt0,Bt1
#define ACC_OFF  (CON_OFF + 64ull)      // float[64*2] segment logit sums
#define CNT_OFF  (ACC_OFF + 512ull)     // int[64] segment counts

// ---------------------------------------------------------------------------
// k0: constants, u-vectors, segment counts (sorted ids -> boundary scan),
//     zero segment accumulators.
// ---------------------------------------------------------------------------
__global__ void prep_kernel(const float* __restrict__ gamma, const float* __restrict__ beta,
                            const float* __restrict__ wout, const int* __restrict__ segids,
                            float* __restrict__ u0, float* __restrict__ u1,
                            float* __restrict__ consts, float* __restrict__ segacc,
                            int* __restrict__ counts) {
    __shared__ int   starts[65];
    __shared__ float cacc[4];
    int tid = threadIdx.x;                       // blockDim = 1024 = HDIM
    if (tid < 128) segacc[tid] = 0.f;
    if (tid < 4)   cacc[tid]   = 0.f;
    if (tid == 0) { starts[0] = 0; starts[64] = T_TOK; }
    __syncthreads();

    float g  = gamma[tid], be = beta[tid];
    float w0 = wout[2 * tid], w1 = wout[2 * tid + 1];
    float a0 = g * w0, a1 = g * w1;
    u0[tid] = a0; u1[tid] = a1;
    float v[4] = {a0, a1, be * w0, be * w1};
#pragma unroll
    for (int q = 0; q < 4; ++q) {
        float x = v[q];
#pragma unroll
        for (int off = 32; off > 0; off >>= 1) x += __shfl_down(x, off, 64);
        if ((tid & 63) == 0) atomicAdd(&cacc[q], x);
    }
    // segment boundaries (ids sorted, all segments non-empty)
    for (int i = tid; i < T_TOK - 1; i += 1024) {
        int s0 = segids[i], s1 = segids[i + 1];
        if (s1 != s0) starts[s1] = i + 1;
    }
    __syncthreads();
    if (tid < 64) counts[tid] = starts[tid + 1] - starts[tid];
    if (tid < 4)  consts[tid] = cacc[tid];
}

// ---------------------------------------------------------------------------
// k1: W [k][col] fp32  ->  Wp fragment-major fp16.
// Wp[((ct*64 + ksg)*64 + lane)*8 + j] = W[ksg*16 + (lane>>5)*8 + j][ct*32 + (lane&31)]
// so a wave's B-fragment load for (col-tile ct, K-step ksg) is one contiguous 1KB read.
// ---------------------------------------------------------------------------
__global__ void wpack_kernel(const float* __restrict__ W, _Float16* __restrict__ Wp) {
    __shared__ float tile[64][65];       // [kloc][cloc]
    int bx = blockIdx.x & 15;            // col tile (64 cols)
    int by = blockIdx.x >> 4;            // k tile (64 k)
    int c0 = bx * 64, k0 = by * 64;
    int t  = threadIdx.x;                // 256 threads
    int kk = t >> 6, cc = t & 63;
#pragma unroll
    for (int i = 0; i < 16; ++i) {
        int kl = kk * 16 + i;
        tile[kl][cc] = W[(size_t)(k0 + kl) * HDIM + c0 + cc];   // coalesced
    }
    __syncthreads();
    int cti  = t >> 7;                   // 0..1
    int ksgi = (t >> 5) & 3;             // 0..3
    int ln   = t & 31;
    int ct   = (c0 >> 5) + cti;
    int ksg  = (k0 >> 4) + ksgi;
#pragma unroll
    for (int lh = 0; lh < 2; ++lh) {
        int l = lh * 32 + ln;
        half8 v;
#pragma unroll
        for (int j = 0; j < 8; ++j)
            v[j] = (_Float16)tile[ksgi * 16 + lh * 8 + j][cti * 32 + ln];
        *(half8*)(Wp + ((size_t)(ct * 64 + ksg) * 64 + l) * 8) = v;  // coalesced 16B/lane
    }
}

// ---------------------------------------------------------------------------
// k2: fused GEMM + residual + LN-functionals + segment partial reduce.
// 1024 blocks x 1024 threads (16 waves); block = 64 rows x full N=1024.
// wave w covers cols [w*64, w*64+64): acc[2][2] of 32x32 -> 64 regs/lane.
// A: fp32 global -> fp16 LDS fragment-chunks, staged per 256-wide K quarter.
// B: packed Wp, one contiguous 1KB coalesced wave-load per fragment (L2-hit).
// ---------------------------------------------------------------------------
#define A_LDS 33280   // 32 khalf-rows * (64 chunks + 1 pad chunk) * 16B

__global__ __launch_bounds__(1024, 4) void gemm_kernel(
    const float* __restrict__ A, const float* __restrict__ R,
    const float* __restrict__ bdense, const _Float16* __restrict__ Wp,
    const float* __restrict__ u0g, const float* __restrict__ u1g,
    const float* __restrict__ consts, const int* __restrict__ segids,
    float* __restrict__ segacc) {
    __shared__ __align__(16) char smem[A_LDS + 512 + 256];
    int tid  = threadIdx.x;
    int lane = tid & 63, wave = tid >> 6;   // 16 waves
    int ln = lane & 31, lh = lane >> 5;
    int rowBase = blockIdx.x * 64;
    int colW    = wave * 64;

    f32x16 acc[2][2];
#pragma unroll
    for (int tr = 0; tr < 2; ++tr)
#pragma unroll
        for (int tc = 0; tc < 2; ++tc)
#pragma unroll
            for (int i = 0; i < 16; ++i) acc[tr][tc][i] = 0.f;

    // B fragment bases: chunk index (ct*64 + ksg), 1KB per chunk
    const _Float16* bp[2];
#pragma unroll
    for (int tc = 0; tc < 2; ++tc)
        bp[tc] = Wp + ((size_t)(wave * 2 + tc) * 64 * 64 + lane) * 8;

    int khalf = tid & 31;    // staging: 8-wide k chunk within quarter
    int mloc0 = tid >> 5;    // staging: row 0..31 (+32 on second iter)

    for (int kq = 0; kq < 4; ++kq) {
        __syncthreads();     // previous quarter fully consumed
        // ---- stage A quarter: 64 rows x 256 k, fp32 -> fp16 chunks ----
#pragma unroll
        for (int i = 0; i < 2; ++i) {
            int mloc = mloc0 + i * 32;
            const float* src = A + (size_t)(rowBase + mloc) * HDIM + kq * 256 + khalf * 8;
            f32x4 a0 = *(const f32x4*)src;
            f32x4 a1 = *(const f32x4*)(src + 4);
            half8 s;
            s[0] = (_Float16)a0[0]; s[1] = (_Float16)a0[1];
            s[2] = (_Float16)a0[2]; s[3] = (_Float16)a0[3];
            s[4] = (_Float16)a1[0]; s[5] = (_Float16)a1[1];
            s[6] = (_Float16)a1[2]; s[7] = (_Float16)a1[3];
            *(half8*)(smem + khalf * 1040 + mloc * 16) = s;   // 1040B pitch
        }
        __syncthreads();
        // ---- K loop: 16 steps of K=16 ----
#pragma unroll
        for (int ks = 0; ks < 16; ++ks) {
            int ksg = kq * 16 + ks;
            half8 afr[2], bfr[2];
#pragma unroll
            for (int tc = 0; tc < 2; ++tc)
                bfr[tc] = *(const half8*)(bp[tc] + (size_t)ksg * 512);  // coalesced 1KB/wave
#pragma unroll
            for (int tr = 0; tr < 2; ++tr)
                afr[tr] = *(const half8*)(smem + (ks * 2 + lh) * 1040 + (tr * 32 + ln) * 16);
#pragma unroll
            for (int tr = 0; tr < 2; ++tr)
#pragma unroll
                for (int tc = 0; tc < 2; ++tc)
                    acc[tr][tc] = __builtin_amdgcn_mfma_f32_32x32x16_f16(
                        afr[tr], bfr[tc], acc[tr][tc], 0, 0, 0);
        }
    }

    // ---- epilogue: h = acc + b + r ; reduce S1,S2,P0,P1 per row ----
    __syncthreads();
    float* red  = (float*)smem;                 // [4][64 rows][32 lanes] = 32KB
#pragma unroll
    for (int i = 0; i < 8; ++i) red[tid + i * 1024] = 0.f;
    float* sval = (float*)(smem + A_LDS);       // [64][2]
    int*   sseg = (int*)(smem + A_LDS + 512);   // [64]
    __syncthreads();

    float bv[2], u0v[2], u1v[2];
#pragma unroll
    for (int tc = 0; tc < 2; ++tc) {
        int c = colW + tc * 32 + ln;
        bv[tc] = bdense[c]; u0v[tc] = u0g[c]; u1v[tc] = u1g[c];
    }
#pragma unroll
    for (int tr = 0; tr < 2; ++tr)
#pragma unroll
        for (int reg = 0; reg < 16; ++reg) {
            int rIT   = (reg & 3) + 8 * (reg >> 2) + 4 * lh;  // C/D row map (m74/m101)
            int row64 = tr * 32 + rIT;
            size_t grow = (size_t)(rowBase + row64);
            float s1 = 0.f, s2 = 0.f, p0 = 0.f, p1 = 0.f;
#pragma unroll
            for (int tc = 0; tc < 2; ++tc) {
                float h = acc[tr][tc][reg] + bv[tc] + R[grow * HDIM + colW + tc * 32 + ln];
                s1 += h; s2 += h * h; p0 += h * u0v[tc]; p1 += h * u1v[tc];
            }
            atomicAdd(&red[row64 * 32 + ln], s1);
            atomicAdd(&red[2048 + row64 * 32 + ln], s2);
            atomicAdd(&red[4096 + row64 * 32 + ln], p0);
            atomicAdd(&red[6144 + row64 * 32 + ln], p1);
        }
    __syncthreads();
    // final reduce: 16 threads per row, skewed f32x2 reads to dodge bank conflicts
    {
        int r = tid >> 4, i = tid & 15;
        int j = (i + r) & 15;
        f32x2 v0 = *(f32x2*)&red[r * 32 + 2 * j];
        f32x2 v1 = *(f32x2*)&red[2048 + r * 32 + 2 * j];
        f32x2 v2 = *(f32x2*)&red[4096 + r * 32 + 2 * j];
        f32x2 v3 = *(f32x2*)&red[6144 + r * 32 + 2 * j];
        float s1 = v0[0] + v0[1], s2 = v1[0] + v1[1];
        float p0 = v2[0] + v2[1], p1 = v3[0] + v3[1];
#pragma unroll
        for (int off = 1; off < 16; off <<= 1) {
            s1 += __shfl_xor(s1, off, 64);
            s2 += __shfl_xor(s2, off, 64);
            p0 += __shfl_xor(p0, off, 64);
            p1 += __shfl_xor(p1, off, 64);
        }
        if (i == 0) {
            float mu  = s1 * (1.f / 1024.f);
            float var = s2 * (1.f / 1024.f) - mu * mu;
            float rsd = rsqrtf(var + 1e-12f);
            sval[r * 2]     = rsd * (p0 - mu * consts[0]) + consts[2];
            sval[r * 2 + 1] = rsd * (p1 - mu * consts[1]) + consts[3];
            sseg[r] = segids[rowBase + r];
        }
    }
    __syncthreads();
    // segment-run combine within the 64 sorted rows; one atomic pair per run
    if (tid < 64) {
        int s = sseg[tid];
        if (tid == 63 || sseg[tid + 1] != s) {
            float a0 = 0.f, a1 = 0.f;
            int rr = tid;
            while (rr >= 0 && sseg[rr] == s) { a0 += sval[rr * 2]; a1 += sval[rr * 2 + 1]; --rr; }
            atomicAdd(&segacc[s * 2],     a0);
            atomicAdd(&segacc[s * 2 + 1], a1);
        }
    }
}

// ---------------------------------------------------------------------------
// k3: logits[b][l] = segacc[b][l] / count[b] + b_out[l]
// ---------------------------------------------------------------------------
__global__ void finalize_kernel(const float* __restrict__ segacc, const int* __restrict__ counts,
                                const float* __restrict__ bout, float* __restrict__ out) {
    int t = threadIdx.x;
    if (t < 128) {
        int s = t >> 1, l = t & 1;
        out[t] = segacc[t] / (float)counts[s] + bout[l];
    }
}

extern "C" void kernel_launch(void* const* d_in, const int* in_sizes, int n_in,
                              void* d_out, int out_size, void* d_ws, size_t ws_size,
                              hipStream_t stream) {
    const float* A      = (const float*)d_in[0];  // sequence_attention_embeddings [T,H]
    const float* R      = (const float*)d_in[1];  // sequence_embeddings [T,H]
    const float* Wd     = (const float*)d_in[2];  // W_dense [H,H]
    const float* bdense = (const float*)d_in[3];  // b_dense [H]
    const float* gamma  = (const float*)d_in[4];  // gamma [H]
    const float* beta   = (const float*)d_in[5];  // beta [H]
    const float* wout   = (const float*)d_in[6];  // W_out [H,2]
    const float* bout   = (const float*)d_in[7];  // b_out [2]
    const int*   segids = (const int*)d_in[8];    // segment_ids [T]
    float* out = (float*)d_out;

    char* ws = (char*)d_ws;
    _Float16* Wp  = (_Float16*)(ws + WP_OFF);
    float* u0     = (float*)(ws + U0_OFF);
    float* u1     = (float*)(ws + U1_OFF);
    float* consts = (float*)(ws + CON_OFF);
    float* segacc = (float*)(ws + ACC_OFF);
    int*   counts = (int*)(ws + CNT_OFF);

    prep_kernel<<<1, 1024, 0, stream>>>(gamma, beta, wout, segids, u0, u1, consts, segacc, counts);
    wpack_kernel<<<256, 256, 0, stream>>>(Wd, Wp);
    gemm_kernel<<<1024, 1024, 0, stream>>>(A, R, bdense, Wp, u0, u1, consts, segids, segacc);
    finalize_kernel<<<1, 128, 0, stream>>>(segacc, counts, bout, out);
}